// Round 6
// baseline (291.075 us; speedup 1.0000x reference)
//
#include <hip/hip_runtime.h>

// B=8, N=4096, Din=128, Dout=256. TT=16 tokens/block -> M = 3*16 = 48 rows.
// bf16 2-way split (hi/mid) + 3 product-class MFMAs = ~24-bit GEMMs (validated:
// absmax 0.5 vs threshold 2.42).
// R9: R8's post-mortem: VGPR stayed 52 (predicted 110+) -> the compiler SANK
// the rolling-prefetch loads back to their uses; MLP never materialized. Also
// VALUBusy arithmetic showed ~5K VALU cyc/wave, the largest issue bucket, much
// of it exact-math sqrt/div expansions (no fast-math).
// This round:
//  (a) pin the prefetch schedule with __builtin_amdgcn_sched_barrier(0) at
//      load/compute boundaries (sparse: ~11 pins) so W/M3 tiles CANNOT sink;
//      rolling depth 2-3 (peak 64 VGPRs of W tiles in flight);
//  (b) replace exact 1/sqrt and divide with v_rsq_f32 / v_rcp_f32 builtins
//      (~1ulp; error << 1.9 absmax headroom): rsqf on SQUARED norms guarded by
//      fmaxf(nsq,1e-24) == reference's max(n,1e-12); rcpf in the epilogue.
//  (c) everything else unchanged from R8 (vectorized phase A, de-unioned LDS
//      76.8KB -> 2 blocks/CU, 2 barriers, epilogue x from Yt stash).
#define TT 16
#define NBLK 2048
#define LDA 136   // aT row stride (bf16): 128 + 8 pad
#define LDY 264   // Yt row stride (bf16): 256 + 8 pad

typedef short s16x8 __attribute__((ext_vector_type(8)));
typedef float f32x4 __attribute__((ext_vector_type(4)));

#define SCHED_FENCE() __builtin_amdgcn_sched_barrier(0)

__device__ __forceinline__ unsigned short f2bf(float f) {
  union { float f; unsigned u; } v; v.f = f;
  unsigned r = v.u + 0x7FFFu + ((v.u >> 16) & 1u);   // RNE; inputs finite
  return (unsigned short)(r >> 16);
}
__device__ __forceinline__ float bf2f(unsigned short h) {
  union { unsigned u; float f; } v; v.u = ((unsigned)h) << 16;
  return v.f;
}
__device__ __forceinline__ void split2(float x, unsigned short& h, unsigned short& m) {
  h = f2bf(x);
  m = f2bf(x - bf2f(h));   // exact subtraction
}

__global__ __launch_bounds__(256) void prep_kernel(
    const float* __restrict__ A, const float* __restrict__ Bm,
    const float* __restrict__ C, const float* __restrict__ W,
    unsigned short* __restrict__ M3h, unsigned short* __restrict__ M3m,
    unsigned short* __restrict__ Wh, unsigned short* __restrict__ Wm) {
  int tid = blockIdx.x * 256 + threadIdx.x;
  if (tid < 128 * 256) {
    unsigned short h, m;
    split2(A[tid] + Bm[tid] + C[tid], h, m);
    M3h[tid] = h; M3m[tid] = m;
  } else {
    int t2 = tid - 128 * 256;
    unsigned short h, m;
    split2(W[t2], h, m);
    Wh[t2] = h; Wm[t2] = m;
  }
}

// rolling-prefetch load macros (all indices compile-time constant)
#define B1LOAD(ks) { \
  b1h[ks][0] = *(const s16x8*)(M3h + fB1 + (ks) * 32); \
  b1m[ks][0] = *(const s16x8*)(M3m + fB1 + (ks) * 32); \
  b1h[ks][1] = *(const s16x8*)(M3h + fB1 + 2048 + (ks) * 32); \
  b1m[ks][1] = *(const s16x8*)(M3m + fB1 + 2048 + (ks) * 32); }

#define W2LOAD(ks) { \
  w2h[ks][0] = *(const s16x8*)(Wh + fB2 + (ks) * 32); \
  w2m[ks][0] = *(const s16x8*)(Wm + fB2 + (ks) * 32); \
  w2h[ks][1] = *(const s16x8*)(Wh + fB2 + 4096 + (ks) * 32); \
  w2m[ks][1] = *(const s16x8*)(Wm + fB2 + 4096 + (ks) * 32); }

#define G1STEP(ks) { \
  const int e0 = (ks) * 32 + quad * 8; \
  _Pragma("unroll") \
  for (int mt = 0; mt < 3; ++mt) { \
    s16x8 ah = *(const s16x8*)(aTh + (mt * 16 + nl) * LDA + e0); \
    s16x8 am = *(const s16x8*)(aTm + (mt * 16 + nl) * LDA + e0); \
    _Pragma("unroll") \
    for (int nt = 0; nt < 2; ++nt) { \
      f32x4 a = acc1[mt][nt]; \
      a = __builtin_amdgcn_mfma_f32_16x16x32_bf16(ah, b1h[ks][nt], a, 0, 0, 0); \
      a = __builtin_amdgcn_mfma_f32_16x16x32_bf16(ah, b1m[ks][nt], a, 0, 0, 0); \
      a = __builtin_amdgcn_mfma_f32_16x16x32_bf16(am, b1h[ks][nt], a, 0, 0, 0); \
      acc1[mt][nt] = a; \
    } \
  } }

#define G2STEP(ks) { \
  const int c0 = (ks) * 32 + quad * 8; \
  _Pragma("unroll") \
  for (int mt = 0; mt < 3; ++mt) { \
    s16x8 ah = *(const s16x8*)(Yth + (mt * 16 + nl) * LDY + c0); \
    s16x8 am = *(const s16x8*)(Ytm + (mt * 16 + nl) * LDY + c0); \
    _Pragma("unroll") \
    for (int nt = 0; nt < 2; ++nt) { \
      f32x4 a = acc2[mt][nt]; \
      a = __builtin_amdgcn_mfma_f32_16x16x32_bf16(ah, w2h[ks][nt], a, 0, 0, 0); \
      a = __builtin_amdgcn_mfma_f32_16x16x32_bf16(ah, w2m[ks][nt], a, 0, 0, 0); \
      a = __builtin_amdgcn_mfma_f32_16x16x32_bf16(am, w2h[ks][nt], a, 0, 0, 0); \
      acc2[mt][nt] = a; \
    } \
  } }

__global__ __launch_bounds__(512, 4) void affine_vnrelu_mfma(
    const float* __restrict__ X, const float* __restrict__ J,
    const unsigned short* __restrict__ M3h, const unsigned short* __restrict__ M3m,
    const unsigned short* __restrict__ Wh, const unsigned short* __restrict__ Wm,
    float* __restrict__ out) {
  __shared__ unsigned short smem[2 * 48 * LDA + 2 * 48 * LDY];  // 76800 B
  unsigned short* aTh = smem;
  unsigned short* aTm = smem + 48 * LDA;
  unsigned short* Yth = smem + 2 * 48 * LDA;
  unsigned short* Ytm = Yth + 48 * LDY;

  const int tid = threadIdx.x;
  const int lane = tid & 63;
  const int w = tid >> 6;          // wave 0..7 -> f slice [32w, 32w+32)
  const int quad = lane >> 4;
  const int nl = lane & 15;
  const long g0 = (long)blockIdx.x * TT;
  const int b = (int)(g0 >> 12);   // N = 4096
  const int n0 = (int)(g0 & 4095);
  const int f0 = w * 32;
  const int fB1 = (f0 + nl) * 128 + quad * 8;
  const int fB2 = (f0 + nl) * 256 + quad * 8;
  const f32x4 zz = {0.f, 0.f, 0.f, 0.f};

  // ---- early issue: first half of GEMM1 B-tiles; pinned so they can't sink
  // into phase A (they stay in flight under its VALU, drain at barrier 1) ----
  s16x8 b1h[4][2], b1m[4][2];
  B1LOAD(0); B1LOAD(1);
  SCHED_FENCE();

  // ---------------- Phase A (vectorized): 1 thread = 4 channels of 1 token --
  {
    int t = tid >> 5;                 // token 0..15
    int dch0 = (tid & 31) * 4;        // channel group
    const float* Xp = X + ((g0 + t) * 128 + dch0) * 3;   // 48B, 16B-aligned
    const float* Jp = J + ((g0 + t) * 128 + dch0) * 6;   // 96B, 16B-aligned
    float xf[12], jf[24];
    #pragma unroll
    for (int q = 0; q < 3; ++q) *(float4*)(xf + 4 * q) = ((const float4*)Xp)[q];
    #pragma unroll
    for (int q = 0; q < 6; ++q) *(float4*)(jf + 4 * q) = ((const float4*)Jp)[q];

    unsigned short hs[3][4], ms[3][4];
    #pragma unroll
    for (int e = 0; e < 4; ++e) {
      float x0 = xf[3 * e], x1 = xf[3 * e + 1], x2 = xf[3 * e + 2];
      float j0 = jf[6 * e],     j1 = jf[6 * e + 1], j2 = jf[6 * e + 2];
      float j3 = jf[6 * e + 3], j4 = jf[6 * e + 4], j5 = jf[6 * e + 5];
      float c00 = j0, c01 = j2, c02 = j4;          // col0 of the 3x2
      float a20 = j1, a21 = j3, a22 = j5;          // col1
      // v_rsq on squared norm; fmaxf(nsq,1e-24) == reference max(n,1e-12)
      float nsq1 = c00 * c00 + c01 * c01 + c02 * c02;
      float inv1 = __builtin_amdgcn_rsqf(fmaxf(nsq1, 1e-24f));
      float b10 = c00 * inv1, b11 = c01 * inv1, b12 = c02 * inv1;
      float pr = b10 * a20 + b11 * a21 + b12 * a22;
      float u0 = a20 - pr * b10, u1 = a21 - pr * b11, u2 = a22 - pr * b12;
      float nsq2 = u0 * u0 + u1 * u1 + u2 * u2;
      float inv2 = __builtin_amdgcn_rsqf(fmaxf(nsq2, 1e-24f));
      float b20 = u0 * inv2, b21 = u1 * inv2, b22 = u2 * inv2;
      float b30 = b11 * b22 - b12 * b21;
      float b31 = b12 * b20 - b10 * b22;
      float b32 = b10 * b21 - b11 * b20;
      split2(b10 * x0 + b11 * x1 + b12 * x2, hs[0][e], ms[0][e]);
      split2(b20 * x0 + b21 * x1 + b22 * x2, hs[1][e], ms[1][e]);
      split2(b30 * x0 + b31 * x1 + b32 * x2, hs[2][e], ms[2][e]);
    }
    #pragma unroll
    for (int i = 0; i < 3; ++i) {
      short4 vh, vm;
      vh.x = hs[i][0]; vh.y = hs[i][1]; vh.z = hs[i][2]; vh.w = hs[i][3];
      vm.x = ms[i][0]; vm.y = ms[i][1]; vm.z = ms[i][2]; vm.w = ms[i][3];
      int ro = (i * 16 + t) * LDA + dch0;
      *(short4*)(aTh + ro) = vh;    // 8B-aligned (LDA even, dch0%4==0)
      *(short4*)(aTm + ro) = vm;
    }
  }
  __syncthreads();   // barrier 1: aT ready

  // ---------------- GEMM1: Y[j][f] = sum_e aT[j][e] * M3[f][e] --------------
  f32x4 acc1[3][2];
  #pragma unroll
  for (int mt = 0; mt < 3; ++mt)
    #pragma unroll
    for (int nt = 0; nt < 2; ++nt) acc1[mt][nt] = zz;

  B1LOAD(2); B1LOAD(3);          // pinned ahead of steps 0-1
  SCHED_FENCE();
  G1STEP(0);
  G1STEP(1);
  G1STEP(2);
  G1STEP(3);

  // ---- issue GEMM2 W-tiles ks0-1 (pinned; drain at barrier 2 under stash) --
  s16x8 w2h[8][2], w2m[8][2];
  W2LOAD(0); W2LOAD(1);
  SCHED_FENCE();

  // ---------------- stash Y as bf16x2; acc1 dies here -----------------------
  #pragma unroll
  for (int mt = 0; mt < 3; ++mt)
    #pragma unroll
    for (int nt = 0; nt < 2; ++nt)
      #pragma unroll
      for (int r = 0; r < 4; ++r) {
        unsigned short h, m;
        split2(acc1[mt][nt][r], h, m);
        int yo = (mt * 16 + quad * 4 + r) * LDY + f0 + nt * 16 + nl;
        Yth[yo] = h; Ytm[yo] = m;
      }
  __syncthreads();   // barrier 2: Yt ready

  // ---------------- GEMM2: d[j][o] = sum_c Yt[j][c] * W[o][c] ---------------
  // Pinned rolling prefetch, depth 2-3: peak W-tile liveness 4 ks = 64 VGPRs;
  // sched_barrier(0) at each boundary stops hipcc sinking loads to their uses
  // (R8 post-mortem: unpinned version collapsed back to VGPR=52, serialized).
  f32x4 acc2[3][2];
  #pragma unroll
  for (int mt = 0; mt < 3; ++mt)
    #pragma unroll
    for (int nt = 0; nt < 2; ++nt) acc2[mt][nt] = zz;

  W2LOAD(2); W2LOAD(3);
  SCHED_FENCE();
  G2STEP(0);
  SCHED_FENCE();
  W2LOAD(4);
  SCHED_FENCE();
  G2STEP(1);
  SCHED_FENCE();
  W2LOAD(5);
  SCHED_FENCE();
  G2STEP(2);
  SCHED_FENCE();
  W2LOAD(6);
  SCHED_FENCE();
  G2STEP(3);
  SCHED_FENCE();
  W2LOAD(7);
  SCHED_FENCE();
  G2STEP(4);
  G2STEP(5);
  G2STEP(6);
  G2STEP(7);

  // ---------------- VN-LeakyReLU + float4 stores ----------------------------
  // x re-read from Yt stash (x̂ = h+m, err ~2^-16·|x| — R6-validated).
  // d_i = acc2[i][nt][r] at f = f0+nt*16+nl, t = quad*4+r.
  #pragma unroll
  for (int nt = 0; nt < 2; ++nt) {
    int f = f0 + nt * 16 + nl;
    float* ob = out + ((long)(b * 256 + f) * 3) * 4096 + n0 + quad * 4;
    float o[3][4];
    #pragma unroll
    for (int r = 0; r < 4; ++r) {
      int row = quad * 4 + r;
      float x0 = bf2f(Yth[row * LDY + f])        + bf2f(Ytm[row * LDY + f]);
      float x1 = bf2f(Yth[(16 + row) * LDY + f]) + bf2f(Ytm[(16 + row) * LDY + f]);
      float x2 = bf2f(Yth[(32 + row) * LDY + f]) + bf2f(Ytm[(32 + row) * LDY + f]);
      float d0 = acc2[0][nt][r], d1 = acc2[1][nt][r], d2 = acc2[2][nt][r];
      float dot = x0 * d0 + x1 * d1 + x2 * d2;
      float dn = d0 * d0 + d1 * d1 + d2 * d2;
      float s = (dot < 0.0f) ? (0.8f * dot * __builtin_amdgcn_rcpf(dn + 1e-6f))
                             : 0.0f;
      o[0][r] = x0 - s * d0;
      o[1][r] = x1 - s * d1;
      o[2][r] = x2 - s * d2;
    }
    #pragma unroll
    for (int i = 0; i < 3; ++i)
      *(float4*)(ob + ((long)i * 4096)) = make_float4(o[i][0], o[i][1], o[i][2], o[i][3]);
  }
}

extern "C" void kernel_launch(void* const* d_in, const int* in_sizes, int n_in,
                              void* d_out, int out_size, void* d_ws, size_t ws_size,
                              hipStream_t stream) {
  const float* X = (const float*)d_in[0];   // [8,4096,128,3]
  const float* J = (const float*)d_in[1];   // [8,4096,128,3,2]
  const float* A = (const float*)d_in[2];   // [256,128]
  const float* B = (const float*)d_in[3];   // [256,128]
  const float* C = (const float*)d_in[4];   // [256,128]
  const float* W = (const float*)d_in[5];   // [256,256]
  unsigned short* M3h = (unsigned short*)d_ws;        // 32768 u16
  unsigned short* M3m = M3h + 128 * 256;
  unsigned short* Wh  = M3m + 128 * 256;              // 65536 u16
  unsigned short* Wm  = Wh + 256 * 256;               // total 384 KB of ws
  float* out = (float*)d_out;               // [8,256,3,4096]

  prep_kernel<<<(128 * 256 + 256 * 256) / 256, 256, 0, stream>>>(
      A, B, C, W, M3h, M3m, Wh, Wm);
  affine_vnrelu_mfma<<<NBLK, 512, 0, stream>>>(
      X, J, M3h, M3m, Wh, Wm, out);
}

// Round 10
// 280.713 us; speedup vs baseline: 1.0369x; 1.0369x over previous
//
#include <hip/hip_runtime.h>

// B=8, N=4096, Din=128, Dout=256. TT=16 tokens/block -> M = 3*16 = 48 rows.
// bf16 2-way split (hi/mid) + 3 product-class MFMAs = ~24-bit GEMMs.
// R10 (4th submit — three GPUAcquisitionTimeouts; kernel has never run):
// ALGEBRAIC FUSION. R5-R9 invariant: ~145-163us regardless of occupancy,
// VALU, barriers -> wall = per-wave global B-operand load latency (~48-57
// loads x ~300cy L2, MLP depth ~1; compiler sinks prefetches, fences only got
// VGPR 52->64). Instead of forcing MLP, remove the loads:
//   d = W @ (M3 @ a) = (W @ M3) @ a,  WM3 = Wdir@(A+B+C) is [256x128],
// precomputed once in prep2 (8.4 MFLOP). Consequences:
//   - GEMM2 K: 256 -> 128 (MFMA/wave 216 -> 144);
//   - GEMM2 A-operand = aT (already in LDS): Yt stash GONE, barrier 2 GONE,
//     epilogue x comes from live acc1 (exact fp32, the R5-validated path);
//   - per-wave global loads 57 -> 41; LDS ops 174 -> ~78; LDS 76.8 -> 26KB.
// Numerics: single bf16x2 rounding of WM3 vs double rounding of bf16(Y) and
// bf16(W) before -> same 24-bit scheme, expected absmax <= ~1 (thr 2.42).
// Kept from R9: vectorized phase A, v_rsq/v_rcp, sched_barrier pins on the
// depth-1 rolling prefetch.
#define TT 16
#define NBLK 2048
#define LDA 136   // aT row stride (bf16): 128 + 8 pad

typedef short s16x8 __attribute__((ext_vector_type(8)));
typedef float f32x4 __attribute__((ext_vector_type(4)));

#define SCHED_FENCE() __builtin_amdgcn_sched_barrier(0)

__device__ __forceinline__ unsigned short f2bf(float f) {
  union { float f; unsigned u; } v; v.f = f;
  unsigned r = v.u + 0x7FFFu + ((v.u >> 16) & 1u);   // RNE; inputs finite
  return (unsigned short)(r >> 16);
}
__device__ __forceinline__ float bf2f(unsigned short h) {
  union { unsigned u; float f; } v; v.u = ((unsigned)h) << 16;
  return v.f;
}
__device__ __forceinline__ void split2(float x, unsigned short& h, unsigned short& m) {
  h = f2bf(x);
  m = f2bf(x - bf2f(h));   // exact subtraction
}

// prep1: M3 = A+B+C -> fp32 buffer (for prep2) + bf16x2 planes (for GEMM1)
__global__ __launch_bounds__(256) void prep1_kernel(
    const float* __restrict__ A, const float* __restrict__ Bm,
    const float* __restrict__ C,
    float* __restrict__ M3f,
    unsigned short* __restrict__ M3h, unsigned short* __restrict__ M3m) {
  int tid = blockIdx.x * 256 + threadIdx.x;   // 0..32767
  float s = A[tid] + Bm[tid] + C[tid];
  M3f[tid] = s;
  unsigned short h, m;
  split2(s, h, m);
  M3h[tid] = h; M3m[tid] = m;
}

// prep2: WM3[o][e] = sum_c W[o][c] * M3f[c][e], split to bf16x2 planes.
// 256 blocks (one per o) x 128 threads (one per e); W row staged in LDS;
// M3f reads are lane-coalesced (consecutive e -> consecutive floats).
__global__ __launch_bounds__(128) void prep2_kernel(
    const float* __restrict__ W, const float* __restrict__ M3f,
    unsigned short* __restrict__ WMh, unsigned short* __restrict__ WMm) {
  __shared__ float wrow[256];
  const int o = blockIdx.x;
  const int e = threadIdx.x;
  wrow[e]       = W[o * 256 + e];
  wrow[e + 128] = W[o * 256 + 128 + e];
  __syncthreads();
  float dot = 0.f;
  #pragma unroll 8
  for (int c = 0; c < 256; ++c) dot += wrow[c] * M3f[c * 128 + e];
  unsigned short h, m;
  split2(dot, h, m);
  WMh[o * 128 + e] = h; WMm[o * 128 + e] = m;
}

// rolling-prefetch load macros (all indices compile-time constant).
// Both weight planes are [256][128] u16; row = f0+nt*16+nl, col = ks*32+quad*8.
#define B1LOAD(ks) { \
  b1h[ks][0] = *(const s16x8*)(M3h + fB + (ks) * 32); \
  b1m[ks][0] = *(const s16x8*)(M3m + fB + (ks) * 32); \
  b1h[ks][1] = *(const s16x8*)(M3h + fB + 2048 + (ks) * 32); \
  b1m[ks][1] = *(const s16x8*)(M3m + fB + 2048 + (ks) * 32); }

#define WMLOAD(ks) { \
  wmh[ks][0] = *(const s16x8*)(WMh + fB + (ks) * 32); \
  wmm[ks][0] = *(const s16x8*)(WMm + fB + (ks) * 32); \
  wmh[ks][1] = *(const s16x8*)(WMh + fB + 2048 + (ks) * 32); \
  wmm[ks][1] = *(const s16x8*)(WMm + fB + 2048 + (ks) * 32); }

#define G1STEP(ks) { \
  const int e0 = (ks) * 32 + quad * 8; \
  _Pragma("unroll") \
  for (int mt = 0; mt < 3; ++mt) { \
    s16x8 ah = *(const s16x8*)(aTh + (mt * 16 + nl) * LDA + e0); \
    s16x8 am = *(const s16x8*)(aTm + (mt * 16 + nl) * LDA + e0); \
    _Pragma("unroll") \
    for (int nt = 0; nt < 2; ++nt) { \
      f32x4 a = acc1[mt][nt]; \
      a = __builtin_amdgcn_mfma_f32_16x16x32_bf16(ah, b1h[ks][nt], a, 0, 0, 0); \
      a = __builtin_amdgcn_mfma_f32_16x16x32_bf16(ah, b1m[ks][nt], a, 0, 0, 0); \
      a = __builtin_amdgcn_mfma_f32_16x16x32_bf16(am, b1h[ks][nt], a, 0, 0, 0); \
      acc1[mt][nt] = a; \
    } \
  } }

#define G2STEP(ks) { \
  const int e0 = (ks) * 32 + quad * 8; \
  _Pragma("unroll") \
  for (int mt = 0; mt < 3; ++mt) { \
    s16x8 ah = *(const s16x8*)(aTh + (mt * 16 + nl) * LDA + e0); \
    s16x8 am = *(const s16x8*)(aTm + (mt * 16 + nl) * LDA + e0); \
    _Pragma("unroll") \
    for (int nt = 0; nt < 2; ++nt) { \
      f32x4 a = acc2[mt][nt]; \
      a = __builtin_amdgcn_mfma_f32_16x16x32_bf16(ah, wmh[ks][nt], a, 0, 0, 0); \
      a = __builtin_amdgcn_mfma_f32_16x16x32_bf16(ah, wmm[ks][nt], a, 0, 0, 0); \
      a = __builtin_amdgcn_mfma_f32_16x16x32_bf16(am, wmh[ks][nt], a, 0, 0, 0); \
      acc2[mt][nt] = a; \
    } \
  } }

__global__ __launch_bounds__(512, 4) void affine_vnrelu_mfma(
    const float* __restrict__ X, const float* __restrict__ J,
    const unsigned short* __restrict__ M3h, const unsigned short* __restrict__ M3m,
    const unsigned short* __restrict__ WMh, const unsigned short* __restrict__ WMm,
    float* __restrict__ out) {
  __shared__ unsigned short smem[2 * 48 * LDA];   // aT hi/mid, 26112 B
  unsigned short* aTh = smem;
  unsigned short* aTm = smem + 48 * LDA;

  const int tid = threadIdx.x;
  const int lane = tid & 63;
  const int w = tid >> 6;          // wave 0..7 -> f slice [32w, 32w+32)
  const int quad = lane >> 4;
  const int nl = lane & 15;
  const long g0 = (long)blockIdx.x * TT;
  const int b = (int)(g0 >> 12);   // N = 4096
  const int n0 = (int)(g0 & 4095);
  const int f0 = w * 32;
  const int fB = (f0 + nl) * 128 + quad * 8;
  const f32x4 zz = {0.f, 0.f, 0.f, 0.f};

  // ---- early issue: GEMM1 ks=0 tiles, pinned in flight through phase A -----
  s16x8 b1h[4][2], b1m[4][2];
  s16x8 wmh[4][2], wmm[4][2];
  B1LOAD(0);
  SCHED_FENCE();

  // ---------------- Phase A (vectorized): 1 thread = 4 channels of 1 token --
  {
    int t = tid >> 5;                 // token 0..15
    int dch0 = (tid & 31) * 4;        // channel group
    const float* Xp = X + ((g0 + t) * 128 + dch0) * 3;   // 48B, 16B-aligned
    const float* Jp = J + ((g0 + t) * 128 + dch0) * 6;   // 96B, 16B-aligned
    float xf[12], jf[24];
    #pragma unroll
    for (int q = 0; q < 3; ++q) *(float4*)(xf + 4 * q) = ((const float4*)Xp)[q];
    #pragma unroll
    for (int q = 0; q < 6; ++q) *(float4*)(jf + 4 * q) = ((const float4*)Jp)[q];

    unsigned short hs[3][4], ms[3][4];
    #pragma unroll
    for (int e = 0; e < 4; ++e) {
      float x0 = xf[3 * e], x1 = xf[3 * e + 1], x2 = xf[3 * e + 2];
      float j0 = jf[6 * e],     j1 = jf[6 * e + 1], j2 = jf[6 * e + 2];
      float j3 = jf[6 * e + 3], j4 = jf[6 * e + 4], j5 = jf[6 * e + 5];
      float c00 = j0, c01 = j2, c02 = j4;          // col0 of the 3x2
      float a20 = j1, a21 = j3, a22 = j5;          // col1
      // v_rsq on squared norm; fmaxf(nsq,1e-24) == reference max(n,1e-12)
      float nsq1 = c00 * c00 + c01 * c01 + c02 * c02;
      float inv1 = __builtin_amdgcn_rsqf(fmaxf(nsq1, 1e-24f));
      float b10 = c00 * inv1, b11 = c01 * inv1, b12 = c02 * inv1;
      float pr = b10 * a20 + b11 * a21 + b12 * a22;
      float u0 = a20 - pr * b10, u1 = a21 - pr * b11, u2 = a22 - pr * b12;
      float nsq2 = u0 * u0 + u1 * u1 + u2 * u2;
      float inv2 = __builtin_amdgcn_rsqf(fmaxf(nsq2, 1e-24f));
      float b20 = u0 * inv2, b21 = u1 * inv2, b22 = u2 * inv2;
      float b30 = b11 * b22 - b12 * b21;
      float b31 = b12 * b20 - b10 * b22;
      float b32 = b10 * b21 - b11 * b20;
      split2(b10 * x0 + b11 * x1 + b12 * x2, hs[0][e], ms[0][e]);
      split2(b20 * x0 + b21 * x1 + b22 * x2, hs[1][e], ms[1][e]);
      split2(b30 * x0 + b31 * x1 + b32 * x2, hs[2][e], ms[2][e]);
    }
    #pragma unroll
    for (int i = 0; i < 3; ++i) {
      short4 vh, vm;
      vh.x = hs[i][0]; vh.y = hs[i][1]; vh.z = hs[i][2]; vh.w = hs[i][3];
      vm.x = ms[i][0]; vm.y = ms[i][1]; vm.z = ms[i][2]; vm.w = ms[i][3];
      int ro = (i * 16 + t) * LDA + dch0;
      *(short4*)(aTh + ro) = vh;    // 8B-aligned (LDA even, dch0%4==0)
      *(short4*)(aTm + ro) = vm;
    }
  }
  __syncthreads();   // the single barrier: aT ready

  // ---------------- GEMM1: Y[j][f] = sum_e aT[j][e] * M3[f][e] --------------
  f32x4 acc1[3][2];
  #pragma unroll
  for (int mt = 0; mt < 3; ++mt)
    #pragma unroll
    for (int nt = 0; nt < 2; ++nt) acc1[mt][nt] = zz;

  B1LOAD(1);
  SCHED_FENCE();
  G1STEP(0);
  B1LOAD(2);
  SCHED_FENCE();
  G1STEP(1);
  B1LOAD(3);
  SCHED_FENCE();
  G1STEP(2);
  WMLOAD(0); WMLOAD(1);      // GEMM2 tiles in flight under last G1 step
  SCHED_FENCE();
  G1STEP(3);

  // ---------------- GEMM2: d[j][o] = sum_e aT[j][e] * WM3[o][e] -------------
  // Same A-operand (aT in LDS), K=128. acc1 stays live for the epilogue.
  f32x4 acc2[3][2];
  #pragma unroll
  for (int mt = 0; mt < 3; ++mt)
    #pragma unroll
    for (int nt = 0; nt < 2; ++nt) acc2[mt][nt] = zz;

  G2STEP(0);
  WMLOAD(2);
  SCHED_FENCE();
  G2STEP(1);
  WMLOAD(3);
  SCHED_FENCE();
  G2STEP(2);
  G2STEP(3);

  // ---------------- VN-LeakyReLU (lane-local, exact fp32 x) + stores --------
  // lane holds x_i = acc1[i][nt][r], d_i = acc2[i][nt][r] at the SAME (f, t):
  // f = f0 + nt*16 + nl, t = quad*4 + r.
  #pragma unroll
  for (int nt = 0; nt < 2; ++nt) {
    int f = f0 + nt * 16 + nl;
    float* ob = out + ((long)(b * 256 + f) * 3) * 4096 + n0 + quad * 4;
    float o[3][4];
    #pragma unroll
    for (int r = 0; r < 4; ++r) {
      float x0 = acc1[0][nt][r], x1 = acc1[1][nt][r], x2 = acc1[2][nt][r];
      float d0 = acc2[0][nt][r], d1 = acc2[1][nt][r], d2 = acc2[2][nt][r];
      float dot = x0 * d0 + x1 * d1 + x2 * d2;
      float dn = d0 * d0 + d1 * d1 + d2 * d2;
      float s = (dot < 0.0f) ? (0.8f * dot * __builtin_amdgcn_rcpf(dn + 1e-6f))
                             : 0.0f;
      o[0][r] = x0 - s * d0;
      o[1][r] = x1 - s * d1;
      o[2][r] = x2 - s * d2;
    }
    #pragma unroll
    for (int i = 0; i < 3; ++i)
      *(float4*)(ob + ((long)i * 4096)) = make_float4(o[i][0], o[i][1], o[i][2], o[i][3]);
  }
}

extern "C" void kernel_launch(void* const* d_in, const int* in_sizes, int n_in,
                              void* d_out, int out_size, void* d_ws, size_t ws_size,
                              hipStream_t stream) {
  const float* X = (const float*)d_in[0];   // [8,4096,128,3]
  const float* J = (const float*)d_in[1];   // [8,4096,128,3,2]
  const float* A = (const float*)d_in[2];   // [256,128]
  const float* B = (const float*)d_in[3];   // [256,128]
  const float* C = (const float*)d_in[4];   // [256,128]
  const float* W = (const float*)d_in[5];   // [256,256]
  unsigned short* M3h = (unsigned short*)d_ws;          // 32768 u16
  unsigned short* M3m = M3h + 128 * 256;                // 32768 u16
  unsigned short* WMh = M3m + 128 * 256;                // 32768 u16
  unsigned short* WMm = WMh + 128 * 256;                // 32768 u16
  float* M3f = (float*)(WMm + 128 * 256);               // 32768 f32; total 384KB
  float* out = (float*)d_out;               // [8,256,3,4096]

  prep1_kernel<<<128, 256, 0, stream>>>(A, B, C, M3f, M3h, M3m);
  prep2_kernel<<<256, 128, 0, stream>>>(W, M3f, WMh, WMm);
  affine_vnrelu_mfma<<<NBLK, 512, 0, stream>>>(
      X, J, M3h, M3m, WMh, WMm, out);
}